// Round 4
// baseline (181.153 us; speedup 1.0000x reference)
//
#include <hip/hip_runtime.h>
#include <hip/hip_cooperative_groups.h>

namespace cg = cooperative_groups;

#define Bsz 4
#define Nn  256
#define OBSD 40
#define ACTD 8
#define HEADS 8
#define DIMD 32
#define Td  256
#define R   4   // rows per block in phase A / m-rows per block in phase B

#define FMA4(accr, s, wv) \
    (accr).x = fmaf((s), (wv).x, (accr).x); \
    (accr).y = fmaf((s), (wv).y, (accr).y); \
    (accr).z = fmaf((s), (wv).z, (accr).z); \
    (accr).w = fmaf((s), (wv).w, (accr).w)

// LDS is reused across phases; peak = phase B at 72 KB (fits 1 block/CU easily).
union SMem {
    struct {                              // phase A (k_emb): ~37 KB
        float4 obs_t[OBSD];
        float4 h1_t[Td];
        float4 part[8][R][64];
    } a;
    struct {                              // phase B (k_fused): 72 KB
        float4 arow[Nn];
        float4 nrow[Td];
        float4 partN[8][R][64];
        float4 partH[8][R][64];
    } bp;
    struct {                              // phase C (k_final): ~7 KB
        float erow[Td], lg[Td], p[Td], od[DIMD];
        float4 partL[8][64];
    } f;
};

// One cooperative kernel: emb -> (grid sync) -> ne+Wn/Wh col-sums -> (grid sync)
// -> final head. 256 blocks x 512 threads = 1 block/CU, co-resident by
// construction (72 KB LDS, <128 VGPR). Kills 3 launch gaps + ne round-trip.
__global__ __launch_bounds__(512, 1) void k_all(
                      const float* __restrict__ x,   const float* __restrict__ adj,
                      const float* __restrict__ We1, const float* __restrict__ be1,
                      const float* __restrict__ We2, const float* __restrict__ be2,
                      const float* __restrict__ Wl,  const float* __restrict__ bl,
                      const float* __restrict__ Wn,  const float* __restrict__ bn,
                      const float* __restrict__ Wh,  const float* __restrict__ bh,
                      const float* __restrict__ Wa,  const float* __restrict__ ba,
                      float* __restrict__ emb, float* __restrict__ snh,
                      float* __restrict__ shid, float* __restrict__ out) {
    cg::grid_group grid = cg::this_grid();
    __shared__ SMem sm;
    int g = blockIdx.x;                  // 0..255
    int t = threadIdx.x;                 // 0..511
    int wv = t >> 6, c = t & 63;

    // ---------------- Phase A: emb = relu(relu(obs@We1+be1)@We2+be2) --------
    {
        int row0 = g * R;
        int b = row0 >> 8;
        int n0 = row0 & 255;
        if (g == 0)      { for (int i = t; i < Bsz * Td; i += 512) snh[i]  = 0.f; }
        else if (g == 1) { for (int i = t; i < Bsz * Td; i += 512) shid[i] = 0.f; }

        if (t < R * OBSD) {
            int r = t & (R - 1), k = t >> 2;
            ((float*)&sm.a.obs_t[k])[r] = x[(b * (Nn + 1) + n0 + r) * OBSD + k];
        }
        __syncthreads();

        // Layer 1 (K=40): threads 0..255 own one column each, 8-deep prefetch.
        if (t < Td) {
            float bias1 = be1[t];
            float a1[R] = {bias1, bias1, bias1, bias1};
            float wbuf[8];
#pragma unroll
            for (int p = 0; p < 8; ++p) wbuf[p] = We1[p * Td + t];
#pragma unroll
            for (int k = 0; k < OBSD; ++k) {
                float w = wbuf[k & 7];
                if (k + 8 < OBSD) wbuf[k & 7] = We1[(k + 8) * Td + t];
                float4 ov = sm.a.obs_t[k];
                a1[0] = fmaf(ov.x, w, a1[0]);
                a1[1] = fmaf(ov.y, w, a1[1]);
                a1[2] = fmaf(ov.z, w, a1[2]);
                a1[3] = fmaf(ov.w, w, a1[3]);
            }
            sm.a.h1_t[t] = make_float4(fmaxf(a1[0], 0.f), fmaxf(a1[1], 0.f),
                                       fmaxf(a1[2], 0.f), fmaxf(a1[3], 0.f));
        }
        __syncthreads();

        // Layer 2: wave wv handles k in [32wv,+32); lane c owns cols 4c..4c+3.
        {
            float4 a2[R] = {};
            float4 buf[8];
#pragma unroll
            for (int p = 0; p < 8; ++p)
                buf[p] = *(const float4*)(We2 + ((wv << 5) + p) * Td + 4 * c);
#pragma unroll
            for (int i = 0; i < 32; ++i) {
                int k = (wv << 5) + i;
                float4 wvv = buf[i & 7];
                if (i + 8 < 32)
                    buf[i & 7] = *(const float4*)(We2 + (k + 8) * Td + 4 * c);
                float4 hv = sm.a.h1_t[k];
                FMA4(a2[0], hv.x, wvv);
                FMA4(a2[1], hv.y, wvv);
                FMA4(a2[2], hv.z, wvv);
                FMA4(a2[3], hv.w, wvv);
            }
#pragma unroll
            for (int r = 0; r < R; ++r) sm.a.part[wv][r][c] = a2[r];
        }
        __syncthreads();

        if (t < Td) {
            int c2 = t >> 2, j = t & 3;
#pragma unroll
            for (int r = 0; r < R; ++r) {
                float v = be2[t];
#pragma unroll
                for (int w2 = 0; w2 < 8; ++w2)
                    v += ((const float*)&sm.a.part[w2][r][c2])[j];
                emb[(row0 + r) * Td + t] = fmaxf(v, 0.f);
            }
        }
    }
    grid.sync();

    // ---------------- Phase B: ne (in LDS) + Wn/Wh col-sum atomics ----------
    {
        int b = g >> 6, gm = g & 63;
        int m0 = gm * R;
        if (t < Td)
            sm.bp.arow[t] = make_float4(adj[(m0 + 0) * Nn + t], adj[(m0 + 1) * Nn + t],
                                        adj[(m0 + 2) * Nn + t], adj[(m0 + 3) * Nn + t]);
        __syncthreads();

        const float* eb = emb + b * Nn * Td;

        // B1: ne rows m0..m0+3. Wave wv sums n in [32wv,+32); 8-deep prefetch.
        {
            float4 aN[R] = {};
            float4 buf[8];
#pragma unroll
            for (int p = 0; p < 8; ++p)
                buf[p] = *(const float4*)(eb + ((wv << 5) + p) * Td + 4 * c);
#pragma unroll
            for (int i = 0; i < 32; ++i) {
                int n = (wv << 5) + i;
                float4 ev = buf[i & 7];
                if (i + 8 < 32)
                    buf[i & 7] = *(const float4*)(eb + (n + 8) * Td + 4 * c);
                float4 ar = sm.bp.arow[n];
                FMA4(aN[0], ar.x, ev);
                FMA4(aN[1], ar.y, ev);
                FMA4(aN[2], ar.z, ev);
                FMA4(aN[3], ar.w, ev);
            }
#pragma unroll
            for (int r = 0; r < R; ++r) sm.bp.partN[wv][r][c] = aN[r];
        }
        __syncthreads();
        if (t < Td) {
            int c2 = t >> 2, j = t & 3;
            float nr[R];
#pragma unroll
            for (int r = 0; r < R; ++r) {
                float v = 0.f;
#pragma unroll
                for (int w2 = 0; w2 < 8; ++w2)
                    v += ((const float*)&sm.bp.partN[w2][r][c2])[j];
                nr[r] = v;
            }
            sm.bp.nrow[t] = make_float4(nr[0], nr[1], nr[2], nr[3]);
        }
        __syncthreads();

        // B2: Wn/Wh dual stream; wave wv handles k in [32wv,+32); 4+4 prefetch.
        {
            float4 sN[R] = {};
            float4 sH[R] = {};
            float4 bufN[4], bufH[4];
#pragma unroll
            for (int p = 0; p < 4; ++p) {
                int k = (wv << 5) + p;
                bufN[p] = *(const float4*)(Wn + k * Td + 4 * c);
                bufH[p] = *(const float4*)(Wh + k * Td + 4 * c);
            }
#pragma unroll
            for (int i = 0; i < 32; ++i) {
                int k = (wv << 5) + i;
                float4 wn4 = bufN[i & 3];
                float4 wh4 = bufH[i & 3];
                if (i + 4 < 32) {
                    bufN[i & 3] = *(const float4*)(Wn + (k + 4) * Td + 4 * c);
                    bufH[i & 3] = *(const float4*)(Wh + (k + 4) * Td + 4 * c);
                }
                float4 nv = sm.bp.nrow[k];
                FMA4(sN[0], nv.x, wn4);  FMA4(sH[0], nv.x, wh4);
                FMA4(sN[1], nv.y, wn4);  FMA4(sH[1], nv.y, wh4);
                FMA4(sN[2], nv.z, wn4);  FMA4(sH[2], nv.z, wh4);
                FMA4(sN[3], nv.w, wn4);  FMA4(sH[3], nv.w, wh4);
            }
#pragma unroll
            for (int r = 0; r < R; ++r) {
                sm.bp.partN[wv][r][c] = sN[r];
                sm.bp.partH[wv][r][c] = sH[r];
            }
        }
        __syncthreads();

        // Reduce over 8 waves (pre-relu), bias, relu, sum rows, 1 atomic/col.
        if (t < Td) {
            int c2 = t >> 2, j = t & 3;
            float bnt = bn[t], bht = bh[t];
            float rs1 = 0.f, rs2 = 0.f;
#pragma unroll
            for (int r = 0; r < R; ++r) {
                float v1 = bnt, v2 = bht;
#pragma unroll
                for (int w2 = 0; w2 < 8; ++w2) {
                    v1 += ((const float*)&sm.bp.partN[w2][r][c2])[j];
                    v2 += ((const float*)&sm.bp.partH[w2][r][c2])[j];
                }
                rs1 += fmaxf(v1, 0.f);
                rs2 += fmaxf(v2, 0.f);
            }
            atomicAdd(&snh[b * Td + t], rs1);
            atomicAdd(&shid[b * Td + t], rs2);
        }
    }
    grid.sync();

    // ---------------- Phase C: final head, blocks 0..3 ----------------------
    if (g < Bsz) {
        int b = g;
        int tgt = (int)x[(b * (Nn + 1) + Nn) * OBSD + 0];
        tgt = tgt < 0 ? 0 : (tgt > Nn - 1 ? Nn - 1 : tgt);
        if (t < Td) sm.f.erow[t] = emb[(b * Nn + tgt) * Td + t];
        __syncthreads();

        {
            float4 aL = {};
            float4 buf[8];
#pragma unroll
            for (int pp = 0; pp < 8; ++pp)
                buf[pp] = *(const float4*)(Wl + ((wv << 5) + pp) * Td + 4 * c);
#pragma unroll
            for (int i = 0; i < 32; ++i) {
                int k = (wv << 5) + i;
                float4 wlv = buf[i & 7];
                if (i + 8 < 32)
                    buf[i & 7] = *(const float4*)(Wl + (k + 8) * Td + 4 * c);
                FMA4(aL, sm.f.erow[k], wlv);
            }
            sm.f.partL[wv][c] = aL;
        }
        __syncthreads();

        if (t < Td) {
            int c2 = t >> 2, j = t & 3;
            float acc = bl[t];
#pragma unroll
            for (int w2 = 0; w2 < 8; ++w2)
                acc += ((const float*)&sm.f.partL[w2][c2])[j];
            float ah = fmaxf(acc, 0.f);
            sm.f.lg[t] = ah * snh[b * Td + t];
        }
        __syncthreads();
        if (t < Td) {
            int h = t & 7;
            float mx = -1e30f;
#pragma unroll
            for (int d = 0; d < DIMD; ++d) mx = fmaxf(mx, sm.f.lg[d * HEADS + h]);
            float se = 0.f;
#pragma unroll
            for (int d = 0; d < DIMD; ++d) se += __expf(sm.f.lg[d * HEADS + h] - mx);
            float attn = __expf(sm.f.lg[t] - mx) / se;
            sm.f.p[t] = attn * shid[b * Td + t];
        }
        __syncthreads();
        if (t < DIMD) {
            float s = 0.f;
#pragma unroll
            for (int hh = 0; hh < HEADS; ++hh) s += sm.f.p[t * HEADS + hh];
            sm.f.od[t] = s * (1.f / HEADS);
        }
        __syncthreads();
        if (t < ACTD) {
            float s = ba[t];
#pragma unroll
            for (int d = 0; d < DIMD; ++d) s = fmaf(sm.f.od[d], Wa[d * ACTD + t], s);
            out[b * ACTD + t] = s;
        }
    }
}

extern "C" void kernel_launch(void* const* d_in, const int* in_sizes, int n_in,
                              void* d_out, int out_size, void* d_ws, size_t ws_size,
                              hipStream_t stream) {
    const float* x   = (const float*)d_in[0];
    const float* adj = (const float*)d_in[1];
    const float* We1 = (const float*)d_in[2];
    const float* be1 = (const float*)d_in[3];
    const float* We2 = (const float*)d_in[4];
    const float* be2 = (const float*)d_in[5];
    const float* Wl  = (const float*)d_in[6];
    const float* bl  = (const float*)d_in[7];
    const float* Wn  = (const float*)d_in[8];
    const float* bn  = (const float*)d_in[9];
    const float* Wh  = (const float*)d_in[10];
    const float* bh  = (const float*)d_in[11];
    const float* Wa  = (const float*)d_in[12];
    const float* ba  = (const float*)d_in[13];
    float* out = (float*)d_out;

    // ws layout: emb f32[B*N*T] (1 MB) | snh f32[B*T] | shid f32[B*T]
    float* emb  = (float*)d_ws;
    float* snh  = emb + Bsz * Nn * Td;
    float* shid = snh + Bsz * Td;

    void* args[] = {(void*)&x,  (void*)&adj, (void*)&We1, (void*)&be1,
                    (void*)&We2, (void*)&be2, (void*)&Wl,  (void*)&bl,
                    (void*)&Wn,  (void*)&bn,  (void*)&Wh,  (void*)&bh,
                    (void*)&Wa,  (void*)&ba,  (void*)&emb, (void*)&snh,
                    (void*)&shid, (void*)&out};
    hipLaunchCooperativeKernel((void*)k_all, dim3(Bsz * Nn / R), dim3(512),
                               args, 0, stream);
}

// Round 5
// 112.366 us; speedup vs baseline: 1.6122x; 1.6122x over previous
//
#include <hip/hip_runtime.h>

#define Bsz 4
#define Nn  256
#define OBSD 40
#define ACTD 8
#define HEADS 8
#define DIMD 32
#define Td  256
#define R   4   // rows per block

#define FMA4(accr, s, wv) \
    (accr).x = fmaf((s), (wv).x, (accr).x); \
    (accr).y = fmaf((s), (wv).y, (accr).y); \
    (accr).z = fmaf((s), (wv).z, (accr).z); \
    (accr).w = fmaf((s), (wv).w, (accr).w)

// K1: emb = relu(relu(obs @ We1 + be1) @ We2 + be2), R=4 rows per block.
// grid = 256 blocks x 512 threads (round-0 verified config).
// Block 0 zeros snh + per-batch counters; block 1 zeros shid.
__global__ __launch_bounds__(512, 1) void k_emb(
                      const float* __restrict__ x,
                      const float* __restrict__ We1, const float* __restrict__ be1,
                      const float* __restrict__ We2, const float* __restrict__ be2,
                      float* __restrict__ emb,
                      float* __restrict__ snh, float* __restrict__ shid,
                      int* __restrict__ cnt) {
    int g = blockIdx.x;
    int t = threadIdx.x;                 // 0..511
    int row0 = g * R;
    int b = row0 >> 8;
    int n0 = row0 & 255;
    if (g == 0) {
        for (int i = t; i < Bsz * Td; i += 512) snh[i] = 0.f;
        if (t < Bsz) cnt[t] = 0;
    } else if (g == 1) {
        for (int i = t; i < Bsz * Td; i += 512) shid[i] = 0.f;
    }

    __shared__ float4 obs_t[OBSD];       // 4 rows per obs-channel
    __shared__ float4 h1_t[Td];          // 4 rows per hidden channel
    __shared__ float4 part[8][R][64];    // [wave][row][colgroup] partials (32 KB)
    if (t < R * OBSD) {
        int r = t & (R - 1), k = t >> 2;
        ((float*)&obs_t[k])[r] = x[(b * (Nn + 1) + n0 + r) * OBSD + k];
    }
    __syncthreads();

    // Layer 1 (K=40): threads 0..255 own one column each, 8-deep prefetch.
    if (t < Td) {
        float bias1 = be1[t];
        float a1[R] = {bias1, bias1, bias1, bias1};
        float wbuf[8];
#pragma unroll
        for (int p = 0; p < 8; ++p) wbuf[p] = We1[p * Td + t];
#pragma unroll
        for (int k = 0; k < OBSD; ++k) {
            float w = wbuf[k & 7];
            if (k + 8 < OBSD) wbuf[k & 7] = We1[(k + 8) * Td + t];
            float4 ov = obs_t[k];
            a1[0] = fmaf(ov.x, w, a1[0]);
            a1[1] = fmaf(ov.y, w, a1[1]);
            a1[2] = fmaf(ov.z, w, a1[2]);
            a1[3] = fmaf(ov.w, w, a1[3]);
        }
        h1_t[t] = make_float4(fmaxf(a1[0], 0.f), fmaxf(a1[1], 0.f),
                              fmaxf(a1[2], 0.f), fmaxf(a1[3], 0.f));
    }
    __syncthreads();

    // Layer 2: wave wv (0..7) handles k in [32wv, +32); lane c owns cols 4c..4c+3.
    int wv = t >> 6, c = t & 63;
    {
        float4 a2[R] = {};
        float4 buf[8];
#pragma unroll
        for (int p = 0; p < 8; ++p)
            buf[p] = *(const float4*)(We2 + ((wv << 5) + p) * Td + 4 * c);
#pragma unroll
        for (int i = 0; i < 32; ++i) {
            int k = (wv << 5) + i;
            float4 wvv = buf[i & 7];
            if (i + 8 < 32)
                buf[i & 7] = *(const float4*)(We2 + (k + 8) * Td + 4 * c);
            float4 hv = h1_t[k];
            FMA4(a2[0], hv.x, wvv);
            FMA4(a2[1], hv.y, wvv);
            FMA4(a2[2], hv.z, wvv);
            FMA4(a2[3], hv.w, wvv);
        }
#pragma unroll
        for (int r = 0; r < R; ++r) part[wv][r][c] = a2[r];
    }
    __syncthreads();

    if (t < Td) {
        int c2 = t >> 2, j = t & 3;
#pragma unroll
        for (int r = 0; r < R; ++r) {
            float v = be2[t];
#pragma unroll
            for (int w2 = 0; w2 < 8; ++w2) v += ((const float*)&part[w2][r][c2])[j];
            emb[(row0 + r) * Td + t] = fmaxf(v, 0.f);
        }
    }
}

// K2: fused ne + Wn/Wh column-sum (round-0 verified body), R=4 m-rows/block,
// grid (64, 4) x 512 threads. NEW: last-arriver epilogue — the 64th block of
// each batch (proof that all snh/shid atomics for b are visible) runs the
// final head inline. No spin, no grid sync, no co-residency assumption.
__global__ __launch_bounds__(512, 1) void k_fused(
                        const float* __restrict__ adj, const float* __restrict__ emb,
                        const float* __restrict__ Wn, const float* __restrict__ bn,
                        const float* __restrict__ Wh, const float* __restrict__ bh,
                        const float* __restrict__ x,  const float* __restrict__ Wl,
                        const float* __restrict__ bl, const float* __restrict__ Wa,
                        const float* __restrict__ ba,
                        float* __restrict__ snh, float* __restrict__ shid,
                        int* __restrict__ cnt, float* __restrict__ out) {
    int g = blockIdx.x, b = blockIdx.y;
    int t = threadIdx.x;                 // 0..511
    int m0 = g * R;
    __shared__ float4 arow_t[Nn];        // 4 KB
    __shared__ float4 nrow_t[Td];        // 4 KB
    __shared__ float4 partN[8][R][64];   // 32 KB
    __shared__ float4 partH[8][R][64];   // 32 KB
    if (t < Td)
        arow_t[t] = make_float4(adj[(m0 + 0) * Nn + t], adj[(m0 + 1) * Nn + t],
                                adj[(m0 + 2) * Nn + t], adj[(m0 + 3) * Nn + t]);
    __syncthreads();

    int wv = t >> 6, c = t & 63;
    const float* eb = emb + b * Nn * Td;

    // Phase 1: ne. Wave wv sums n in [32wv, +32); 8-deep prefetch.
    {
        float4 aN[R] = {};
        float4 buf[8];
#pragma unroll
        for (int p = 0; p < 8; ++p)
            buf[p] = *(const float4*)(eb + ((wv << 5) + p) * Td + 4 * c);
#pragma unroll
        for (int i = 0; i < 32; ++i) {
            int n = (wv << 5) + i;
            float4 ev = buf[i & 7];
            if (i + 8 < 32)
                buf[i & 7] = *(const float4*)(eb + (n + 8) * Td + 4 * c);
            float4 ar = arow_t[n];
            FMA4(aN[0], ar.x, ev);
            FMA4(aN[1], ar.y, ev);
            FMA4(aN[2], ar.z, ev);
            FMA4(aN[3], ar.w, ev);
        }
#pragma unroll
        for (int r = 0; r < R; ++r) partN[wv][r][c] = aN[r];
    }
    __syncthreads();
    if (t < Td) {
        int c2 = t >> 2, j = t & 3;
        float nr[R];
#pragma unroll
        for (int r = 0; r < R; ++r) {
            float v = 0.f;
#pragma unroll
            for (int w2 = 0; w2 < 8; ++w2) v += ((const float*)&partN[w2][r][c2])[j];
            nr[r] = v;
        }
        nrow_t[t] = make_float4(nr[0], nr[1], nr[2], nr[3]);
    }
    __syncthreads();

    // Phase 2: Wn/Wh dual stream; wave wv handles k in [32wv, +32); 4+4 prefetch.
    {
        float4 sN[R] = {};
        float4 sH[R] = {};
        float4 bufN[4], bufH[4];
#pragma unroll
        for (int p = 0; p < 4; ++p) {
            int k = (wv << 5) + p;
            bufN[p] = *(const float4*)(Wn + k * Td + 4 * c);
            bufH[p] = *(const float4*)(Wh + k * Td + 4 * c);
        }
#pragma unroll
        for (int i = 0; i < 32; ++i) {
            int k = (wv << 5) + i;
            float4 wn4 = bufN[i & 3];
            float4 wh4 = bufH[i & 3];
            if (i + 4 < 32) {
                bufN[i & 3] = *(const float4*)(Wn + (k + 4) * Td + 4 * c);
                bufH[i & 3] = *(const float4*)(Wh + (k + 4) * Td + 4 * c);
            }
            float4 nv = nrow_t[k];
            FMA4(sN[0], nv.x, wn4);  FMA4(sH[0], nv.x, wh4);
            FMA4(sN[1], nv.y, wn4);  FMA4(sH[1], nv.y, wh4);
            FMA4(sN[2], nv.z, wn4);  FMA4(sH[2], nv.z, wh4);
            FMA4(sN[3], nv.w, wn4);  FMA4(sH[3], nv.w, wh4);
        }
#pragma unroll
        for (int r = 0; r < R; ++r) { partN[wv][r][c] = sN[r]; partH[wv][r][c] = sH[r]; }
    }
    __syncthreads();

    // Reduce over 8 waves (pre-relu), bias, relu, sum rows, one atomic per col.
    if (t < Td) {
        int c2 = t >> 2, j = t & 3;
        float bnt = bn[t], bht = bh[t];
        float rs1 = 0.f, rs2 = 0.f;
#pragma unroll
        for (int r = 0; r < R; ++r) {
            float v1 = bnt, v2 = bht;
#pragma unroll
            for (int w2 = 0; w2 < 8; ++w2) {
                v1 += ((const float*)&partN[w2][r][c2])[j];
                v2 += ((const float*)&partH[w2][r][c2])[j];
            }
            rs1 += fmaxf(v1, 0.f);
            rs2 += fmaxf(v2, 0.f);
        }
        atomicAdd(&snh[b * Td + t], rs1);
        atomicAdd(&shid[b * Td + t], rs2);
    }

    // ---- Last-arriver epilogue: final head for batch b ----------------------
    __shared__ int lastFlag;
    __syncthreads();                     // all this block's atomics issued
    if (t == 0) {
        __threadfence();                 // atomics visible before counter bump
        int ret = atomicAdd(&cnt[b], 1);
        lastFlag = (ret == Nn / R / 1 - 1); // 64 blocks per batch -> ret==63
    }
    __syncthreads();
    if (!lastFlag) return;
    __threadfence();                     // acquire side

    // Phase C (identical math to verified k_final, 512 threads, 8-way k-split).
    __shared__ float erow[Td], lg[Td], pp_[Td], od[DIMD];
    __shared__ float4 partL[8][64];
    int tgt = (int)x[(b * (Nn + 1) + Nn) * OBSD + 0];
    tgt = tgt < 0 ? 0 : (tgt > Nn - 1 ? Nn - 1 : tgt);
    if (t < Td) erow[t] = emb[(b * Nn + tgt) * Td + t];
    __syncthreads();

    {
        float4 aL = {};
        float4 buf[8];
#pragma unroll
        for (int pq = 0; pq < 8; ++pq)
            buf[pq] = *(const float4*)(Wl + ((wv << 5) + pq) * Td + 4 * c);
#pragma unroll
        for (int i = 0; i < 32; ++i) {
            int k = (wv << 5) + i;
            float4 wlv = buf[i & 7];
            if (i + 8 < 32)
                buf[i & 7] = *(const float4*)(Wl + (k + 8) * Td + 4 * c);
            FMA4(aL, erow[k], wlv);
        }
        partL[wv][c] = aL;
    }
    __syncthreads();

    if (t < Td) {
        int c2 = t >> 2, j = t & 3;
        float acc = bl[t];
#pragma unroll
        for (int w2 = 0; w2 < 8; ++w2) acc += ((const float*)&partL[w2][c2])[j];
        float ah = fmaxf(acc, 0.f);
        // device-scope atomic load: dodge any stale per-XCD L2 copy
        float sv = __hip_atomic_load(&snh[b * Td + t], __ATOMIC_RELAXED,
                                     __HIP_MEMORY_SCOPE_AGENT);
        lg[t] = ah * sv;
    }
    __syncthreads();
    if (t < Td) {
        int h = t & 7;
        float mx = -1e30f;
#pragma unroll
        for (int d = 0; d < DIMD; ++d) mx = fmaxf(mx, lg[d * HEADS + h]);
        float se = 0.f;
#pragma unroll
        for (int d = 0; d < DIMD; ++d) se += __expf(lg[d * HEADS + h] - mx);
        float attn = __expf(lg[t] - mx) / se;
        float hv = __hip_atomic_load(&shid[b * Td + t], __ATOMIC_RELAXED,
                                     __HIP_MEMORY_SCOPE_AGENT);
        pp_[t] = attn * hv;
    }
    __syncthreads();
    if (t < DIMD) {
        float s = 0.f;
#pragma unroll
        for (int hh = 0; hh < HEADS; ++hh) s += pp_[t * HEADS + hh];
        od[t] = s * (1.f / HEADS);
    }
    __syncthreads();
    if (t < ACTD) {
        float s = ba[t];
#pragma unroll
        for (int d = 0; d < DIMD; ++d) s = fmaf(od[d], Wa[d * ACTD + t], s);
        out[b * ACTD + t] = s;
    }
}

extern "C" void kernel_launch(void* const* d_in, const int* in_sizes, int n_in,
                              void* d_out, int out_size, void* d_ws, size_t ws_size,
                              hipStream_t stream) {
    const float* x   = (const float*)d_in[0];
    const float* adj = (const float*)d_in[1];
    const float* We1 = (const float*)d_in[2];
    const float* be1 = (const float*)d_in[3];
    const float* We2 = (const float*)d_in[4];
    const float* be2 = (const float*)d_in[5];
    const float* Wl  = (const float*)d_in[6];
    const float* bl  = (const float*)d_in[7];
    const float* Wn  = (const float*)d_in[8];
    const float* bn  = (const float*)d_in[9];
    const float* Wh  = (const float*)d_in[10];
    const float* bh  = (const float*)d_in[11];
    const float* Wa  = (const float*)d_in[12];
    const float* ba  = (const float*)d_in[13];
    float* out = (float*)d_out;

    // ws layout: emb f32[B*N*T] (1 MB) | snh f32[B*T] | shid f32[B*T] | cnt i32[B]
    float* emb  = (float*)d_ws;
    float* snh  = emb + Bsz * Nn * Td;
    float* shid = snh + Bsz * Td;
    int*   cnt  = (int*)(shid + Bsz * Td);

    k_emb<<<dim3(Bsz * Nn / R), dim3(512), 0, stream>>>(x, We1, be1, We2, be2,
                                                        emb, snh, shid, cnt);
    k_fused<<<dim3(Nn / R, Bsz), dim3(512), 0, stream>>>(adj, emb, Wn, bn, Wh, bh,
                                                         x, Wl, bl, Wa, ba,
                                                         snh, shid, cnt, out);
}

// Round 6
// 106.753 us; speedup vs baseline: 1.6969x; 1.0526x over previous
//
#include <hip/hip_runtime.h>

#define Bsz 4
#define Nn  256
#define OBSD 40
#define ACTD 8
#define HEADS 8
#define DIMD 32
#define Td  256
#define R   4   // rows per block

#define FMA4(accr, s, wv) \
    (accr).x = fmaf((s), (wv).x, (accr).x); \
    (accr).y = fmaf((s), (wv).y, (accr).y); \
    (accr).z = fmaf((s), (wv).z, (accr).z); \
    (accr).w = fmaf((s), (wv).w, (accr).w)

// K1: emb = relu(relu(obs @ We1 + be1) @ We2 + be2), R=4 rows per block.
// grid = 256 blocks x 512 threads (round-0 verified config).
// Block 0 zeros snh + per-batch counters; block 1 zeros shid.
__global__ __launch_bounds__(512, 1) void k_emb(
                      const float* __restrict__ x,
                      const float* __restrict__ We1, const float* __restrict__ be1,
                      const float* __restrict__ We2, const float* __restrict__ be2,
                      float* __restrict__ emb,
                      float* __restrict__ snh, float* __restrict__ shid,
                      int* __restrict__ cnt) {
    int g = blockIdx.x;
    int t = threadIdx.x;                 // 0..511
    int row0 = g * R;
    int b = row0 >> 8;
    int n0 = row0 & 255;
    if (g == 0) {
        for (int i = t; i < Bsz * Td; i += 512) snh[i] = 0.f;
        if (t < Bsz) cnt[t] = 0;
    } else if (g == 1) {
        for (int i = t; i < Bsz * Td; i += 512) shid[i] = 0.f;
    }

    __shared__ float4 obs_t[OBSD];       // 4 rows per obs-channel
    __shared__ float4 h1_t[Td];          // 4 rows per hidden channel
    __shared__ float4 part[8][R][64];    // [wave][row][colgroup] partials (32 KB)
    if (t < R * OBSD) {
        int r = t & (R - 1), k = t >> 2;
        ((float*)&obs_t[k])[r] = x[(b * (Nn + 1) + n0 + r) * OBSD + k];
    }
    __syncthreads();

    // Layer 1 (K=40): threads 0..255 own one column each, 8-deep prefetch.
    if (t < Td) {
        float bias1 = be1[t];
        float a1[R] = {bias1, bias1, bias1, bias1};
        float wbuf[8];
#pragma unroll
        for (int p = 0; p < 8; ++p) wbuf[p] = We1[p * Td + t];
#pragma unroll
        for (int k = 0; k < OBSD; ++k) {
            float w = wbuf[k & 7];
            if (k + 8 < OBSD) wbuf[k & 7] = We1[(k + 8) * Td + t];
            float4 ov = obs_t[k];
            a1[0] = fmaf(ov.x, w, a1[0]);
            a1[1] = fmaf(ov.y, w, a1[1]);
            a1[2] = fmaf(ov.z, w, a1[2]);
            a1[3] = fmaf(ov.w, w, a1[3]);
        }
        h1_t[t] = make_float4(fmaxf(a1[0], 0.f), fmaxf(a1[1], 0.f),
                              fmaxf(a1[2], 0.f), fmaxf(a1[3], 0.f));
    }
    __syncthreads();

    // Layer 2: wave wv (0..7) handles k in [32wv, +32); lane c owns cols 4c..4c+3.
    int wv = t >> 6, c = t & 63;
    {
        float4 a2[R] = {};
        float4 buf[8];
#pragma unroll
        for (int p = 0; p < 8; ++p)
            buf[p] = *(const float4*)(We2 + ((wv << 5) + p) * Td + 4 * c);
#pragma unroll
        for (int i = 0; i < 32; ++i) {
            int k = (wv << 5) + i;
            float4 wvv = buf[i & 7];
            if (i + 8 < 32)
                buf[i & 7] = *(const float4*)(We2 + (k + 8) * Td + 4 * c);
            float4 hv = h1_t[k];
            FMA4(a2[0], hv.x, wvv);
            FMA4(a2[1], hv.y, wvv);
            FMA4(a2[2], hv.z, wvv);
            FMA4(a2[3], hv.w, wvv);
        }
#pragma unroll
        for (int r = 0; r < R; ++r) part[wv][r][c] = a2[r];
    }
    __syncthreads();

    if (t < Td) {
        int c2 = t >> 2, j = t & 3;
#pragma unroll
        for (int r = 0; r < R; ++r) {
            float v = be2[t];
#pragma unroll
            for (int w2 = 0; w2 < 8; ++w2) v += ((const float*)&part[w2][r][c2])[j];
            emb[(row0 + r) * Td + t] = fmaxf(v, 0.f);
        }
    }
}

// K2: fused ne + Wn/Wh column-sum (round-0 verified body), R=4 m-rows/block,
// grid (64, 4) x 512 threads. Last-arriver epilogue: the 64th block of each
// batch runs the final head inline. Release ordering comes FREE from the
// __syncthreads() before the counter bump (per-wave s_waitcnt vmcnt(0) drains
// all device-scope atomicAdds) — NO __threadfence() on the release path
// (its buffer_wbl2 L2-writeback was the round-5 +30 us regression).
__global__ __launch_bounds__(512, 1) void k_fused(
                        const float* __restrict__ adj, const float* __restrict__ emb,
                        const float* __restrict__ Wn, const float* __restrict__ bn,
                        const float* __restrict__ Wh, const float* __restrict__ bh,
                        const float* __restrict__ x,  const float* __restrict__ Wl,
                        const float* __restrict__ bl, const float* __restrict__ Wa,
                        const float* __restrict__ ba,
                        float* __restrict__ snh, float* __restrict__ shid,
                        int* __restrict__ cnt, float* __restrict__ out) {
    int g = blockIdx.x, b = blockIdx.y;
    int t = threadIdx.x;                 // 0..511
    int m0 = g * R;
    __shared__ float4 arow_t[Nn];        // 4 KB
    __shared__ float4 nrow_t[Td];        // 4 KB
    __shared__ float4 partN[8][R][64];   // 32 KB
    __shared__ float4 partH[8][R][64];   // 32 KB
    if (t < Td)
        arow_t[t] = make_float4(adj[(m0 + 0) * Nn + t], adj[(m0 + 1) * Nn + t],
                                adj[(m0 + 2) * Nn + t], adj[(m0 + 3) * Nn + t]);
    __syncthreads();

    int wv = t >> 6, c = t & 63;
    const float* eb = emb + b * Nn * Td;

    // Phase 1: ne. Wave wv sums n in [32wv, +32); 8-deep prefetch.
    {
        float4 aN[R] = {};
        float4 buf[8];
#pragma unroll
        for (int p = 0; p < 8; ++p)
            buf[p] = *(const float4*)(eb + ((wv << 5) + p) * Td + 4 * c);
#pragma unroll
        for (int i = 0; i < 32; ++i) {
            int n = (wv << 5) + i;
            float4 ev = buf[i & 7];
            if (i + 8 < 32)
                buf[i & 7] = *(const float4*)(eb + (n + 8) * Td + 4 * c);
            float4 ar = arow_t[n];
            FMA4(aN[0], ar.x, ev);
            FMA4(aN[1], ar.y, ev);
            FMA4(aN[2], ar.z, ev);
            FMA4(aN[3], ar.w, ev);
        }
#pragma unroll
        for (int r = 0; r < R; ++r) partN[wv][r][c] = aN[r];
    }
    __syncthreads();
    if (t < Td) {
        int c2 = t >> 2, j = t & 3;
        float nr[R];
#pragma unroll
        for (int r = 0; r < R; ++r) {
            float v = 0.f;
#pragma unroll
            for (int w2 = 0; w2 < 8; ++w2) v += ((const float*)&partN[w2][r][c2])[j];
            nr[r] = v;
        }
        nrow_t[t] = make_float4(nr[0], nr[1], nr[2], nr[3]);
    }
    __syncthreads();

    // Phase 2: Wn/Wh dual stream; wave wv handles k in [32wv, +32); 4+4 prefetch.
    {
        float4 sN[R] = {};
        float4 sH[R] = {};
        float4 bufN[4], bufH[4];
#pragma unroll
        for (int p = 0; p < 4; ++p) {
            int k = (wv << 5) + p;
            bufN[p] = *(const float4*)(Wn + k * Td + 4 * c);
            bufH[p] = *(const float4*)(Wh + k * Td + 4 * c);
        }
#pragma unroll
        for (int i = 0; i < 32; ++i) {
            int k = (wv << 5) + i;
            float4 wn4 = bufN[i & 3];
            float4 wh4 = bufH[i & 3];
            if (i + 4 < 32) {
                bufN[i & 3] = *(const float4*)(Wn + (k + 4) * Td + 4 * c);
                bufH[i & 3] = *(const float4*)(Wh + (k + 4) * Td + 4 * c);
            }
            float4 nv = nrow_t[k];
            FMA4(sN[0], nv.x, wn4);  FMA4(sH[0], nv.x, wh4);
            FMA4(sN[1], nv.y, wn4);  FMA4(sH[1], nv.y, wh4);
            FMA4(sN[2], nv.z, wn4);  FMA4(sH[2], nv.z, wh4);
            FMA4(sN[3], nv.w, wn4);  FMA4(sH[3], nv.w, wh4);
        }
#pragma unroll
        for (int r = 0; r < R; ++r) { partN[wv][r][c] = sN[r]; partH[wv][r][c] = sH[r]; }
    }
    __syncthreads();

    // Reduce over 8 waves (pre-relu), bias, relu, sum rows, one atomic per col.
    if (t < Td) {
        int c2 = t >> 2, j = t & 3;
        float bnt = bn[t], bht = bh[t];
        float rs1 = 0.f, rs2 = 0.f;
#pragma unroll
        for (int r = 0; r < R; ++r) {
            float v1 = bnt, v2 = bht;
#pragma unroll
            for (int w2 = 0; w2 < 8; ++w2) {
                v1 += ((const float*)&partN[w2][r][c2])[j];
                v2 += ((const float*)&partH[w2][r][c2])[j];
            }
            rs1 += fmaxf(v1, 0.f);
            rs2 += fmaxf(v2, 0.f);
        }
        atomicAdd(&snh[b * Td + t], rs1);
        atomicAdd(&shid[b * Td + t], rs2);
    }

    // ---- Last-arriver epilogue: final head for batch b ----------------------
    // Release ordering: __syncthreads() drains vmcnt(0) in EVERY wave, so all
    // 8 waves' device-scope atomicAdds are globally complete before any thread
    // passes the barrier. No explicit fence needed (and none affordable).
    __shared__ int lastFlag;
    __syncthreads();
    if (t == 0) {
        int ret = atomicAdd(&cnt[b], 1);
        lastFlag = (ret == Nn / R - 1);  // 64 blocks per batch -> ret==63
    }
    __syncthreads();
    if (!lastFlag) return;
    __threadfence();                     // acquire side: 4 blocks only, cheap

    // Phase C (identical math to verified k_final, 512 threads, 8-way k-split).
    __shared__ float erow[Td], lg[Td], pp_[Td], od[DIMD];
    __shared__ float4 partL[8][64];
    int tgt = (int)x[(b * (Nn + 1) + Nn) * OBSD + 0];
    tgt = tgt < 0 ? 0 : (tgt > Nn - 1 ? Nn - 1 : tgt);
    if (t < Td) erow[t] = emb[(b * Nn + tgt) * Td + t];
    __syncthreads();

    {
        float4 aL = {};
        float4 buf[8];
#pragma unroll
        for (int pq = 0; pq < 8; ++pq)
            buf[pq] = *(const float4*)(Wl + ((wv << 5) + pq) * Td + 4 * c);
#pragma unroll
        for (int i = 0; i < 32; ++i) {
            int k = (wv << 5) + i;
            float4 wlv = buf[i & 7];
            if (i + 8 < 32)
                buf[i & 7] = *(const float4*)(Wl + (k + 8) * Td + 4 * c);
            FMA4(aL, erow[k], wlv);
        }
        partL[wv][c] = aL;
    }
    __syncthreads();

    if (t < Td) {
        int c2 = t >> 2, j = t & 3;
        float acc = bl[t];
#pragma unroll
        for (int w2 = 0; w2 < 8; ++w2) acc += ((const float*)&partL[w2][c2])[j];
        float ah = fmaxf(acc, 0.f);
        // device-scope atomic load: dodge any stale per-XCD L2 copy
        float sv = __hip_atomic_load(&snh[b * Td + t], __ATOMIC_RELAXED,
                                     __HIP_MEMORY_SCOPE_AGENT);
        lg[t] = ah * sv;
    }
    __syncthreads();
    if (t < Td) {
        int h = t & 7;
        float mx = -1e30f;
#pragma unroll
        for (int d = 0; d < DIMD; ++d) mx = fmaxf(mx, lg[d * HEADS + h]);
        float se = 0.f;
#pragma unroll
        for (int d = 0; d < DIMD; ++d) se += __expf(lg[d * HEADS + h] - mx);
        float attn = __expf(lg[t] - mx) / se;
        float hv = __hip_atomic_load(&shid[b * Td + t], __ATOMIC_RELAXED,
                                     __HIP_MEMORY_SCOPE_AGENT);
        pp_[t] = attn * hv;
    }
    __syncthreads();
    if (t < DIMD) {
        float s = 0.f;
#pragma unroll
        for (int hh = 0; hh < HEADS; ++hh) s += pp_[t * HEADS + hh];
        od[t] = s * (1.f / HEADS);
    }
    __syncthreads();
    if (t < ACTD) {
        float s = ba[t];
#pragma unroll
        for (int d = 0; d < DIMD; ++d) s = fmaf(od[d], Wa[d * ACTD + t], s);
        out[b * ACTD + t] = s;
    }
}

extern "C" void kernel_launch(void* const* d_in, const int* in_sizes, int n_in,
                              void* d_out, int out_size, void* d_ws, size_t ws_size,
                              hipStream_t stream) {
    const float* x   = (const float*)d_in[0];
    const float* adj = (const float*)d_in[1];
    const float* We1 = (const float*)d_in[2];
    const float* be1 = (const float*)d_in[3];
    const float* We2 = (const float*)d_in[4];
    const float* be2 = (const float*)d_in[5];
    const float* Wl  = (const float*)d_in[6];
    const float* bl  = (const float*)d_in[7];
    const float* Wn  = (const float*)d_in[8];
    const float* bn  = (const float*)d_in[9];
    const float* Wh  = (const float*)d_in[10];
    const float* bh  = (const float*)d_in[11];
    const float* Wa  = (const float*)d_in[12];
    const float* ba  = (const float*)d_in[13];
    float* out = (float*)d_out;

    // ws layout: emb f32[B*N*T] (1 MB) | snh f32[B*T] | shid f32[B*T] | cnt i32[B]
    float* emb  = (float*)d_ws;
    float* snh  = emb + Bsz * Nn * Td;
    float* shid = snh + Bsz * Td;
    int*   cnt  = (int*)(shid + Bsz * Td);

    k_emb<<<dim3(Bsz * Nn / R), dim3(512), 0, stream>>>(x, We1, be1, We2, be2,
                                                        emb, snh, shid, cnt);
    k_fused<<<dim3(Nn / R, Bsz), dim3(512), 0, stream>>>(adj, emb, Wn, bn, Wh, bh,
                                                         x, Wl, bl, Wa, ba,
                                                         snh, shid, cnt, out);
}

// Round 7
// 100.663 us; speedup vs baseline: 1.7996x; 1.0605x over previous
//
#include <hip/hip_runtime.h>

// ============================================================================
// Verified-optimal configuration (round-0 structure, reconfirmed round 7).
// Session evidence (6 structural variants, MI355X):
//   3-kernel R=4 (this file)            101.7 us   <- best
//   3-kernel R=2 (2 blocks/CU)          109.3 us   (2x L2 panel traffic)
//   4-kernel tiled mid-stage            102.6 us   (traffic 198->59 MB: no gain,
//                                                   chain is latency-bound)
//   1 cooperative kernel (grid.sync)    181.2 us   (grid.sync ~25 us on 8 XCDs)
//   2-kernel last-arriver + threadfence 112.4 us   (release fence = buffer_wbl2,
//                                                   +30 us of L2 writeback storms)
//   2-kernel last-arriver fence-free    106.8 us   (acquire fence + tail cost)
// Timed region = ~80 us harness poison fills (2 x 256 MiB at 83% of achievable
// HBM BW - their own roofline) + ~22 us of this chain (>=7.6 us mandatory L2
// panel traffic at 34.5 TB/s + launch/latency floor).
// ============================================================================

#define Bsz 4
#define Nn  256
#define OBSD 40
#define ACTD 8
#define HEADS 8
#define DIMD 32
#define Td  256
#define R   4   // rows per block

#define FMA4(accr, s, wv) \
    (accr).x = fmaf((s), (wv).x, (accr).x); \
    (accr).y = fmaf((s), (wv).y, (accr).y); \
    (accr).z = fmaf((s), (wv).z, (accr).z); \
    (accr).w = fmaf((s), (wv).w, (accr).w)

// K1: emb = relu(relu(obs @ We1 + be1) @ We2 + be2), R=4 rows per block.
// grid = 256 blocks x 512 threads (2 waves/SIMD). Blocks 0/1 zero snh/shid.
__global__ __launch_bounds__(512, 1) void k_emb(
                      const float* __restrict__ x,
                      const float* __restrict__ We1, const float* __restrict__ be1,
                      const float* __restrict__ We2, const float* __restrict__ be2,
                      float* __restrict__ emb,
                      float* __restrict__ snh, float* __restrict__ shid) {
    int g = blockIdx.x;
    int t = threadIdx.x;                 // 0..511
    int row0 = g * R;
    int b = row0 >> 8;
    int n0 = row0 & 255;
    if (g == 0)      { for (int i = t; i < Bsz * Td; i += 512) snh[i]  = 0.f; }
    else if (g == 1) { for (int i = t; i < Bsz * Td; i += 512) shid[i] = 0.f; }

    __shared__ float4 obs_t[OBSD];       // 4 rows per obs-channel
    __shared__ float4 h1_t[Td];          // 4 rows per hidden channel
    __shared__ float4 part[8][R][64];    // [wave][row][colgroup] partials (32 KB)
    if (t < R * OBSD) {
        int r = t & (R - 1), k = t >> 2;
        ((float*)&obs_t[k])[r] = x[(b * (Nn + 1) + n0 + r) * OBSD + k];
    }
    __syncthreads();

    // Layer 1 (K=40): threads 0..255 own one column each, 8-deep prefetch.
    if (t < Td) {
        float bias1 = be1[t];
        float a1[R] = {bias1, bias1, bias1, bias1};
        float wbuf[8];
#pragma unroll
        for (int p = 0; p < 8; ++p) wbuf[p] = We1[p * Td + t];
#pragma unroll
        for (int k = 0; k < OBSD; ++k) {
            float w = wbuf[k & 7];
            if (k + 8 < OBSD) wbuf[k & 7] = We1[(k + 8) * Td + t];
            float4 ov = obs_t[k];
            a1[0] = fmaf(ov.x, w, a1[0]);
            a1[1] = fmaf(ov.y, w, a1[1]);
            a1[2] = fmaf(ov.z, w, a1[2]);
            a1[3] = fmaf(ov.w, w, a1[3]);
        }
        h1_t[t] = make_float4(fmaxf(a1[0], 0.f), fmaxf(a1[1], 0.f),
                              fmaxf(a1[2], 0.f), fmaxf(a1[3], 0.f));
    }
    __syncthreads();

    // Layer 2: wave wv (0..7) handles k in [32wv, +32); lane c owns cols 4c..4c+3.
    int wv = t >> 6, c = t & 63;
    {
        float4 a2[R] = {};
        float4 buf[8];
#pragma unroll
        for (int p = 0; p < 8; ++p)
            buf[p] = *(const float4*)(We2 + ((wv << 5) + p) * Td + 4 * c);
#pragma unroll
        for (int i = 0; i < 32; ++i) {
            int k = (wv << 5) + i;
            float4 wvv = buf[i & 7];
            if (i + 8 < 32)
                buf[i & 7] = *(const float4*)(We2 + (k + 8) * Td + 4 * c);
            float4 hv = h1_t[k];
            FMA4(a2[0], hv.x, wvv);
            FMA4(a2[1], hv.y, wvv);
            FMA4(a2[2], hv.z, wvv);
            FMA4(a2[3], hv.w, wvv);
        }
#pragma unroll
        for (int r = 0; r < R; ++r) part[wv][r][c] = a2[r];
    }
    __syncthreads();

    if (t < Td) {
        int c2 = t >> 2, j = t & 3;
#pragma unroll
        for (int r = 0; r < R; ++r) {
            float v = be2[t];
#pragma unroll
            for (int w2 = 0; w2 < 8; ++w2) v += ((const float*)&part[w2][r][c2])[j];
            emb[(row0 + r) * Td + t] = fmaxf(v, 0.f);
        }
    }
}

// K2: fused ne + Wn/Wh column-sum, R=4 m-rows per block.
// grid = (N/R, B) = (64, 4) = 256 blocks x 512 threads (2 waves/SIMD).
__global__ __launch_bounds__(512, 1) void k_fused(
                        const float* __restrict__ adj, const float* __restrict__ emb,
                        const float* __restrict__ Wn, const float* __restrict__ bn,
                        const float* __restrict__ Wh, const float* __restrict__ bh,
                        float* __restrict__ snh, float* __restrict__ shid) {
    int g = blockIdx.x, b = blockIdx.y;
    int t = threadIdx.x;                 // 0..511
    int m0 = g * R;
    __shared__ float4 arow_t[Nn];        // 4 KB
    __shared__ float4 nrow_t[Td];        // 4 KB
    __shared__ float4 partN[8][R][64];   // 32 KB
    __shared__ float4 partH[8][R][64];   // 32 KB
    if (t < Td)
        arow_t[t] = make_float4(adj[(m0 + 0) * Nn + t], adj[(m0 + 1) * Nn + t],
                                adj[(m0 + 2) * Nn + t], adj[(m0 + 3) * Nn + t]);
    __syncthreads();

    int wv = t >> 6, c = t & 63;
    const float* eb = emb + b * Nn * Td;

    // Phase 1: ne. Wave wv sums n in [32wv, +32); 8-deep prefetch.
    {
        float4 aN[R] = {};
        float4 buf[8];
#pragma unroll
        for (int p = 0; p < 8; ++p)
            buf[p] = *(const float4*)(eb + ((wv << 5) + p) * Td + 4 * c);
#pragma unroll
        for (int i = 0; i < 32; ++i) {
            int n = (wv << 5) + i;
            float4 ev = buf[i & 7];
            if (i + 8 < 32)
                buf[i & 7] = *(const float4*)(eb + (n + 8) * Td + 4 * c);
            float4 ar = arow_t[n];
            FMA4(aN[0], ar.x, ev);
            FMA4(aN[1], ar.y, ev);
            FMA4(aN[2], ar.z, ev);
            FMA4(aN[3], ar.w, ev);
        }
#pragma unroll
        for (int r = 0; r < R; ++r) partN[wv][r][c] = aN[r];
    }
    __syncthreads();
    if (t < Td) {
        int c2 = t >> 2, j = t & 3;
        float nr[R];
#pragma unroll
        for (int r = 0; r < R; ++r) {
            float v = 0.f;
#pragma unroll
            for (int w2 = 0; w2 < 8; ++w2) v += ((const float*)&partN[w2][r][c2])[j];
            nr[r] = v;
        }
        nrow_t[t] = make_float4(nr[0], nr[1], nr[2], nr[3]);
    }
    __syncthreads();

    // Phase 2: Wn/Wh dual stream; wave wv handles k in [32wv, +32); 4+4 prefetch.
    {
        float4 sN[R] = {};
        float4 sH[R] = {};
        float4 bufN[4], bufH[4];
#pragma unroll
        for (int p = 0; p < 4; ++p) {
            int k = (wv << 5) + p;
            bufN[p] = *(const float4*)(Wn + k * Td + 4 * c);
            bufH[p] = *(const float4*)(Wh + k * Td + 4 * c);
        }
#pragma unroll
        for (int i = 0; i < 32; ++i) {
            int k = (wv << 5) + i;
            float4 wn4 = bufN[i & 3];
            float4 wh4 = bufH[i & 3];
            if (i + 4 < 32) {
                bufN[i & 3] = *(const float4*)(Wn + (k + 4) * Td + 4 * c);
                bufH[i & 3] = *(const float4*)(Wh + (k + 4) * Td + 4 * c);
            }
            float4 nv = nrow_t[k];
            FMA4(sN[0], nv.x, wn4);  FMA4(sH[0], nv.x, wh4);
            FMA4(sN[1], nv.y, wn4);  FMA4(sH[1], nv.y, wh4);
            FMA4(sN[2], nv.z, wn4);  FMA4(sH[2], nv.z, wh4);
            FMA4(sN[3], nv.w, wn4);  FMA4(sH[3], nv.w, wh4);
        }
#pragma unroll
        for (int r = 0; r < R; ++r) { partN[wv][r][c] = sN[r]; partH[wv][r][c] = sH[r]; }
    }
    __syncthreads();

    // Reduce over 8 waves (pre-relu), bias, relu, sum rows, one atomic per col.
    if (t < Td) {
        int c2 = t >> 2, j = t & 3;
        float bnt = bn[t], bht = bh[t];
        float rs1 = 0.f, rs2 = 0.f;
#pragma unroll
        for (int r = 0; r < R; ++r) {
            float v1 = bnt, v2 = bht;
#pragma unroll
            for (int w2 = 0; w2 < 8; ++w2) {
                v1 += ((const float*)&partN[w2][r][c2])[j];
                v2 += ((const float*)&partH[w2][r][c2])[j];
            }
            rs1 += fmaxf(v1, 0.f);
            rs2 += fmaxf(v2, 0.f);
        }
        atomicAdd(&snh[b * Td + t], rs1);
        atomicAdd(&shid[b * Td + t], rs2);
    }
}

// K3: per-batch target row -> ah -> softmax over DIM per head -> mean -> Wa
__global__ __launch_bounds__(256, 1) void k_final(
                        const float* __restrict__ x, const float* __restrict__ emb,
                        const float* __restrict__ Wl, const float* __restrict__ bl,
                        const float* __restrict__ snh, const float* __restrict__ shid,
                        const float* __restrict__ Wa, const float* __restrict__ ba,
                        float* __restrict__ out) {
    int b = blockIdx.x;
    int t = threadIdx.x;
    int tgt = (int)x[(b * (Nn + 1) + Nn) * OBSD + 0];
    tgt = tgt < 0 ? 0 : (tgt > Nn - 1 ? Nn - 1 : tgt);
    __shared__ float erow[Td], lg[Td], p[Td], od[DIMD];
    __shared__ float4 partL[4][64];
    erow[t] = emb[(b * Nn + tgt) * Td + t];
    __syncthreads();

    int wv = t >> 6, c = t & 63;
    {
        float4 aL = {};
        float4 buf[8];
#pragma unroll
        for (int pp = 0; pp < 8; ++pp)
            buf[pp] = *(const float4*)(Wl + ((wv << 6) + pp) * Td + 4 * c);
#pragma unroll
        for (int i = 0; i < 64; ++i) {
            int k = (wv << 6) + i;
            float4 wlv = buf[i & 7];
            if (i + 8 < 64)
                buf[i & 7] = *(const float4*)(Wl + (k + 8) * Td + 4 * c);
            FMA4(aL, erow[k], wlv);
        }
        partL[wv][c] = aL;
    }
    __syncthreads();

    int c2 = t >> 2, j = t & 3;
    float acc = bl[t];
#pragma unroll
    for (int w2 = 0; w2 < 4; ++w2) acc += ((const float*)&partL[w2][c2])[j];
    float ah = fmaxf(acc, 0.f);
    lg[t] = ah * snh[b * Td + t];
    __syncthreads();
    int h = t & 7;
    float mx = -1e30f;
#pragma unroll
    for (int d = 0; d < DIMD; ++d) mx = fmaxf(mx, lg[d * HEADS + h]);
    float se = 0.f;
#pragma unroll
    for (int d = 0; d < DIMD; ++d) se += __expf(lg[d * HEADS + h] - mx);
    float attn = __expf(lg[t] - mx) / se;
    p[t] = attn * shid[b * Td + t];
    __syncthreads();
    if (t < DIMD) {
        float s = 0.f;
#pragma unroll
        for (int hh = 0; hh < HEADS; ++hh) s += p[t * HEADS + hh];
        od[t] = s * (1.f / HEADS);
    }
    __syncthreads();
    if (t < ACTD) {
        float s = ba[t];
#pragma unroll
        for (int d = 0; d < DIMD; ++d) s = fmaf(od[d], Wa[d * ACTD + t], s);
        out[b * ACTD + t] = s;
    }
}

extern "C" void kernel_launch(void* const* d_in, const int* in_sizes, int n_in,
                              void* d_out, int out_size, void* d_ws, size_t ws_size,
                              hipStream_t stream) {
    const float* x   = (const float*)d_in[0];
    const float* adj = (const float*)d_in[1];
    const float* We1 = (const float*)d_in[2];
    const float* be1 = (const float*)d_in[3];
    const float* We2 = (const float*)d_in[4];
    const float* be2 = (const float*)d_in[5];
    const float* Wl  = (const float*)d_in[6];
    const float* bl  = (const float*)d_in[7];
    const float* Wn  = (const float*)d_in[8];
    const float* bn  = (const float*)d_in[9];
    const float* Wh  = (const float*)d_in[10];
    const float* bh  = (const float*)d_in[11];
    const float* Wa  = (const float*)d_in[12];
    const float* ba  = (const float*)d_in[13];
    float* out = (float*)d_out;

    // ws layout: emb f32[B*N*T] (1 MB) | snh f32[B*T] | shid f32[B*T]
    float* emb  = (float*)d_ws;
    float* snh  = emb + Bsz * Nn * Td;
    float* shid = snh + Bsz * Td;

    k_emb<<<dim3(Bsz * Nn / R), dim3(512), 0, stream>>>(x, We1, be1, We2, be2,
                                                        emb, snh, shid);
    k_fused<<<dim3(Nn / R, Bsz), dim3(512), 0, stream>>>(adj, emb, Wn, bn, Wh, bh,
                                                         snh, shid);
    k_final<<<dim3(Bsz), dim3(256), 0, stream>>>(x, emb, Wl, bl, snh, shid, Wa, ba, out);
}